// Round 4
// baseline (258.980 us; speedup 1.0000x reference)
//
#include <hip/hip_runtime.h>
#include <hip/hip_bf16.h>
#include <stdint.h>

#define L_DIM 384
#define MD    256      // M_DIM
#define CC    32       // C
#define ZD    128      // Z_DIM
#define NB    512      // N (batch) = K of the big GEMM
#define K2    1024     // C*C
#define MROWS 12288    // L*C

typedef __attribute__((ext_vector_type(4)))  float f32x4;
typedef __attribute__((ext_vector_type(16))) float f32x16;
typedef __attribute__((ext_vector_type(8)))  short bf16x8;

typedef __attribute__((address_space(1))) unsigned char* gcp;
typedef __attribute__((address_space(3))) unsigned char* lcp;

#define SBAR()  __builtin_amdgcn_s_barrier()
#define LGKM0() asm volatile("s_waitcnt lgkmcnt(0)" ::: "memory")
#define VMW(n)  asm volatile("s_waitcnt vmcnt(" #n ")" ::: "memory")
#define PRIO1() __builtin_amdgcn_s_setprio(1)
#define PRIO0() __builtin_amdgcn_s_setprio(0)

__device__ __forceinline__ unsigned short f2bf(float x) {
    union { float f; unsigned u; } v; v.f = x;
    unsigned r = v.u + 0x7fffu + ((v.u >> 16) & 1u);   // round-to-nearest-even
    return (unsigned short)(r >> 16);
}

__device__ __forceinline__ uint2 pack4(unsigned short a, unsigned short b,
                                       unsigned short c, unsigned short d) {
    uint2 r; r.x = (unsigned)a | ((unsigned)b << 16);
    r.y = (unsigned)c | ((unsigned)d << 16); return r;
}

// ---------------------------------------------------------------------------
// prep: w3 -> MFMA B-fragment order w3frag[ks][zg][lane][8], k2' = b*32+a
// (b-major so op tile writes vectorize). w1/w2 -> wfrag for ln_proj.
__global__ __launch_bounds__(256) void prep_kernel(
    const float* __restrict__ w1, const float* __restrict__ w2,
    const float* __restrict__ w3,
    unsigned short* __restrict__ w3frag, unsigned short* __restrict__ wfrag)
{
    int idx = blockIdx.x * 256 + threadIdx.x;          // 147456 total
    if (idx < 131072) {
        int e = idx & 7, lane = (idx >> 3) & 63, zg = (idx >> 9) & 7, ks = idx >> 12;
        int k2p = ks * 32 + ((lane >> 4) << 3) + e;    // k2' = b*32 + a
        int wrow = (k2p & 31) * 32 + (k2p >> 5);       // = a*32 + b
        int z  = zg * 16 + (lane & 15);
        w3frag[idx] = f2bf(w3[(size_t)wrow * ZD + z]);
    } else {
        int j = idx - 131072;                           // 16384
        int e = j & 7, lane = (j >> 3) & 63, nf = (j >> 9) & 3, ks = j >> 11;
        int c = nf * 16 + (lane & 15);
        int d = ks * 32 + ((lane >> 4) << 3) + e;
        float v = (c < CC) ? w2[d * CC + c] : w1[d * CC + (c - CC)];
        wfrag[j] = f2bf(v);
    }
}

// ---------------------------------------------------------------------------
// Kernel A: LayerNorm + dual projection (a = o@w2+b2, b = o@w1+b1) via MFMA.
__global__ __launch_bounds__(256, 4) void ln_proj_kernel(
    const float* __restrict__ mm, const float* __restrict__ gamma, const float* __restrict__ beta,
    const unsigned short* __restrict__ wfrag,
    const float* __restrict__ b1, const float* __restrict__ b2,
    unsigned short* __restrict__ At, unsigned short* __restrict__ Bt)
{
    __shared__ alignas(16) char o_b[32768];            // [64 rows][512 B] swizzled

    const int tid = threadIdx.x, wv = tid >> 6, lane = tid & 63;
    const int l0 = blockIdx.y * 2;
    const int n0 = blockIdx.x * 32;

    const int l_loc = wv >> 1;
    const int nbase = (wv & 1) << 4;
    const int l_g = l0 + l_loc;
    f32x4 g4 = *(const f32x4*)(gamma + lane * 4);
    f32x4 e4 = *(const f32x4*)(beta + lane * 4);

    #pragma unroll 4
    for (int r = 0; r < 16; ++r) {
        int row_loc = wv * 16 + r;
        int n_g = n0 + nbase + r;
        const float* src = mm + ((size_t)n_g * L_DIM + l_g) * MD + lane * 4;
        f32x4 x = *(const f32x4*)src;
        float s  = x[0] + x[1] + x[2] + x[3];
        float s2 = x[0]*x[0] + x[1]*x[1] + x[2]*x[2] + x[3]*x[3];
        #pragma unroll
        for (int off = 32; off > 0; off >>= 1) {
            s  += __shfl_xor(s,  off);
            s2 += __shfl_xor(s2, off);
        }
        float mu  = s * (1.0f / MD);
        float var = s2 * (1.0f / MD) - mu * mu;
        float rs  = rsqrtf(var + 1e-5f);
        unsigned short o0 = f2bf((x[0] - mu) * rs * g4[0] + e4[0]);
        unsigned short o1 = f2bf((x[1] - mu) * rs * g4[1] + e4[1]);
        unsigned short o2 = f2bf((x[2] - mu) * rs * g4[2] + e4[2]);
        unsigned short o3 = f2bf((x[3] - mu) * rs * g4[3] + e4[3]);
        *(uint2*)(o_b + row_loc * 512 + ((lane * 8) ^ ((row_loc & 7) << 4))) = pack4(o0, o1, o2, o3);
    }
    // wave-private rows -> no barrier needed

    f32x4 acc[4] = {{0,0,0,0},{0,0,0,0},{0,0,0,0},{0,0,0,0}};
    const int lrow = lane & 15;
    const int kq16 = (lane >> 4) << 4;
    const int arow = wv * 16 + lrow;
    #pragma unroll
    for (int ks = 0; ks < 8; ++ks) {
        bf16x8 a = *(const bf16x8*)(o_b + arow * 512 + ((ks * 64 + kq16) ^ ((arow & 7) << 4)));
        #pragma unroll
        for (int nf = 0; nf < 4; ++nf) {
            bf16x8 b = *(const bf16x8*)(wfrag + (size_t)((ks * 4 + nf) * 64 + lane) * 8);
            acc[nf] = __builtin_amdgcn_mfma_f32_16x16x32_bf16(a, b, acc[nf], 0, 0, 0);
        }
    }

    const int rr0 = wv * 16 + ((lane >> 4) << 2);
    const int n_gw = n0 + (rr0 & 31);
    const int l_gw = l0 + (rr0 >> 5);
    #pragma unroll
    for (int nf = 0; nf < 4; ++nf) {
        int c = nf * 16 + lrow;
        float bias = (c < CC) ? b2[c] : b1[c - CC];
        unsigned short ob0 = f2bf(acc[nf][0] + bias);
        unsigned short ob1 = f2bf(acc[nf][1] + bias);
        unsigned short ob2 = f2bf(acc[nf][2] + bias);
        unsigned short ob3 = f2bf(acc[nf][3] + bias);
        unsigned short* dst = ((c < CC) ? At : Bt) + (size_t)(l_gw * CC + (c & 31)) * NB + n_gw;
        *(uint2*)dst = pack4(ob0, ob1, ob2, ob3);
    }
}

// ---------------------------------------------------------------------------
// Kernel B: 256x256 op-tile GEMM via 32x32x16 MFMA, 2 phases/K-tile,
// counted vmcnt (VMW(4)@Q1/Q3), barrier-free tail, fused w3 epilogue.
__global__ __launch_bounds__(512, 2) void opm_kernel(
    const unsigned short* __restrict__ At, const unsigned short* __restrict__ Bt,
    const unsigned short* __restrict__ w3frag, const float* __restrict__ b3,
    float* __restrict__ Z)
{
    __shared__ alignas(128) char smem[131072];         // A:[2][256][64] B:[2][256][64]
    char* const Ab = smem;
    char* const Bb = smem + 65536;

    const int tid = threadIdx.x, wv = tid >> 6, lane = tid & 63;

    // T1: XCD-aware remap (8 XCDs x 6-i-band, j-major walk within band)
    const int lin = blockIdx.y * 48 + blockIdx.x;
    const int xcd = lin & 7, chunk = lin >> 3;
    const int i0 = (xcd * 6 + (chunk % 6)) * 256;
    const int j0 = (chunk / 6) * 256;

    const int mrow = lane & 31;                        // row/col within 32-frag
    const int kb16 = (lane >> 5) << 4;                 // k byte offset (0/16)
    const int swz  = (mrow & 7) << 4;                  // hoisted XOR swizzle
    const int wr = (wv >> 2) * 128, wc = (wv & 3) * 64;

    auto stage = [&](const unsigned short* __restrict__ src, int tile0, int kt,
                     int half, int isA) {
        #pragma unroll
        for (int q = 0; q < 2; ++q) {
            int rl0 = q * 64 + wv * 8;
            int rl  = rl0 + (lane >> 3);
            int rc  = isA ? ((rl  & 63) + ((rl  >> 6) << 7) + half * 64)
                          : ((rl  & 31) + ((rl  >> 5) << 6) + half * 32);
            int rc0 = isA ? ((rl0 & 63) + ((rl0 >> 6) << 7) + half * 64)
                          : ((rl0 & 31) + ((rl0 >> 5) << 6) + half * 32);
            const unsigned short* g = src + (size_t)(tile0 + rc) * NB + kt * 64
                                      + (((lane & 7) ^ (lane >> 3)) << 3);
            char* l = (isA ? Ab : Bb) + (kt & 1) * 32768 + rc0 * 128;  // wave-uniform
            __builtin_amdgcn_global_load_lds((gcp)g, (lcp)l, 16, 0, 0);
        }
    };

    f32x16 acc[4][2] = {};
    bf16x8 av[2][4], bv[2][4];

    auto rdA32 = [&](const char* ab, int mhalf) {
        #pragma unroll
        for (int mfl = 0; mfl < 2; ++mfl) {
            const char* p = ab + (wr + (mhalf * 2 + mfl) * 32 + mrow) * 128;
            #pragma unroll
            for (int ks = 0; ks < 4; ++ks)
                av[mfl][ks] = *(const bf16x8*)(p + ((ks * 32 + kb16) ^ swz));
        }
    };
    auto rdB32 = [&](const char* bb) {
        #pragma unroll
        for (int nf = 0; nf < 2; ++nf) {
            const char* p = bb + (wc + nf * 32 + mrow) * 128;
            #pragma unroll
            for (int ks = 0; ks < 4; ++ks)
                bv[nf][ks] = *(const bf16x8*)(p + ((ks * 32 + kb16) ^ swz));
        }
    };
    auto MM32 = [&](int mhalf) {
        #pragma unroll
        for (int mfl = 0; mfl < 2; ++mfl)
            #pragma unroll
            for (int nf = 0; nf < 2; ++nf)
                #pragma unroll
                for (int ks = 0; ks < 4; ++ks)
                    acc[mhalf * 2 + mfl][nf] = __builtin_amdgcn_mfma_f32_32x32x16_bf16(
                        av[mfl][ks], bv[nf][ks], acc[mhalf * 2 + mfl][nf], 0, 0, 0);
    };

    // --- prologue: tile0 full + tile1 half0; publish tile0 ---
    stage(At, i0, 0, 0, 1); stage(Bt, j0, 0, 0, 0);
    stage(At, i0, 0, 1, 1); stage(Bt, j0, 0, 1, 0);
    stage(At, i0, 1, 0, 1); stage(Bt, j0, 1, 0, 0);
    VMW(4);
    SBAR();

    const char* a0 = Ab;           const char* b0 = Bb;
    const char* a1 = Ab + 32768;   const char* b1 = Bb + 32768;

    // --- main loop: t=0..2, tiles (2t, 2t+1); stages: d=2t+1 tail-half, c=2t+2, d'=2t+3 h0
    #pragma unroll
    for (int t = 0; t < 3; ++t) {
        // Q0: tile 2t, M-half0 (reads A-h0 + all B)
        rdA32(a0, 0); rdB32(b0);
        stage(At, i0, 2*t + 1, 1, 1); stage(Bt, j0, 2*t + 1, 1, 0);
        SBAR(); LGKM0(); PRIO1(); MM32(0); PRIO0(); SBAR();
        // Q1: tile 2t, M-half1
        rdA32(a0, 1);
        stage(At, i0, 2*t + 2, 0, 1); stage(Bt, j0, 2*t + 2, 0, 0);
        SBAR(); LGKM0(); PRIO1(); MM32(1); PRIO0(); VMW(4); SBAR();
        // Q2: tile 2t+1, M-half0
        rdA32(a1, 0); rdB32(b1);
        stage(At, i0, 2*t + 2, 1, 1); stage(Bt, j0, 2*t + 2, 1, 0);
        SBAR(); LGKM0(); PRIO1(); MM32(0); PRIO0(); SBAR();
        // Q3: tile 2t+1, M-half1
        rdA32(a1, 1);
        stage(At, i0, 2*t + 3, 0, 1); stage(Bt, j0, 2*t + 3, 0, 0);
        SBAR(); LGKM0(); PRIO1(); MM32(1); PRIO0(); VMW(4); SBAR();
    }

    // --- tail: tiles 6 (buf0), 7 (buf1) ---
    // T0: tile6 M-half0; last stage (tile7 half1)
    rdA32(a0, 0); rdB32(b0);
    stage(At, i0, 7, 1, 1); stage(Bt, j0, 7, 1, 0);
    SBAR(); LGKM0(); PRIO1(); MM32(0); PRIO0(); SBAR();
    // T1: tile6 M-half1; drain all staging, publish tile7
    rdA32(a0, 1);
    SBAR(); LGKM0(); PRIO1(); MM32(1); PRIO0(); VMW(0); SBAR();
    // T2/T3: tile7, barrier-free (no pending LDS writes); compiler schedules
    rdA32(a1, 0); rdB32(b1);
    MM32(0);
    rdA32(a1, 1);
    MM32(1);
    __syncthreads();   // all waves done reading A/B before op-write reuses smem

    // ---- fused w3 epilogue ----
    char* const opb = smem;                            // 64 pairs x 2048 B
    const int lrow = lane & 15;
    const int kq16 = (lane >> 4) << 4;
    const int pfb = (wv >> 2) * 2, zgb = (wv & 3) * 2;
    const int row0 = pfb * 16 + lrow, row1 = row0 + 16;
    const int lq = lane >> 4;

    auto ldW = [&](int ks, int zg) -> bf16x8 {
        return *(const bf16x8*)(w3frag + (size_t)((ks * 8 + zg) * 64 + lane) * 8);
    };
    auto ldP = [&](int row, int ks) -> bf16x8 {
        int g = ks * 4 + lq;
        int b = g >> 2, jj = g & 3;
        int inner = (b * 64 + jj * 16) ^ (((b >> 1) & 7) << 4) ^ ((row & 7) << 4);
        return *(const bf16x8*)(opb + row * 2048 + inner);
    };

    // early-issue first w3 loads (hide under op-write)
    bf16x8 wA0 = ldW(0, zgb), wA1 = ldW(0, zgb + 1);
    bf16x8 wB0 = ldW(1, zgb), wB1 = ldW(1, zgb + 1);

    // write op tile (scaled, bf16), b-major k2' = b*32+a, 8B vector stores.
    // 32x32 C/D layout: col = lane&31, row = (reg&3) + 8*(reg>>2) + 4*(lane>>5)
    const float scale = 1.0f / (float)NB;
    const int bcol = lane & 31;
    const int hq4  = (lane >> 5) << 2;
    #pragma unroll
    for (int mf = 0; mf < 4; ++mf) {
        #pragma unroll
        for (int nf = 0; nf < 2; ++nf) {
            int j_loc = ((wc >> 5) + nf);
            int pl = (((wr >> 5) + mf) << 3) | j_loc;
            int swp = (((bcol >> 1) & 7) << 4) ^ ((pl & 7) << 4);
            #pragma unroll
            for (int q = 0; q < 4; ++q) {
                int a0e = q * 8 + hq4;
                int inner = (bcol * 64 + a0e * 2) ^ swp;
                *(uint2*)(opb + pl * 2048 + inner) =
                    pack4(f2bf(acc[mf][nf][4*q+0] * scale), f2bf(acc[mf][nf][4*q+1] * scale),
                          f2bf(acc[mf][nf][4*q+2] * scale), f2bf(acc[mf][nf][4*q+3] * scale));
            }
        }
    }
    __syncthreads();

    // z-loop: 2-deep software pipeline (w3 from L2, op from LDS)
    f32x4 acc2[2][2] = {};
    bf16x8 pA0 = ldP(row0, 0), pA1 = ldP(row1, 0);
    bf16x8 pB0 = ldP(row0, 1), pB1 = ldP(row1, 1);
    for (int ks = 0; ks < 32; ks += 2) {
        bf16x8 wN0 = {}, wN1 = {}, pN0 = {}, pN1 = {};
        bf16x8 wM0 = {}, wM1 = {}, pM0 = {}, pM1 = {};
        if (ks + 2 < 32) {
            wN0 = ldW(ks + 2, zgb); wN1 = ldW(ks + 2, zgb + 1);
            pN0 = ldP(row0, ks + 2); pN1 = ldP(row1, ks + 2);
            wM0 = ldW(ks + 3, zgb); wM1 = ldW(ks + 3, zgb + 1);
            pM0 = ldP(row0, ks + 3); pM1 = ldP(row1, ks + 3);
        }
        PRIO1();
        acc2[0][0] = __builtin_amdgcn_mfma_f32_16x16x32_bf16(pA0, wA0, acc2[0][0], 0, 0, 0);
        acc2[0][1] = __builtin_amdgcn_mfma_f32_16x16x32_bf16(pA0, wA1, acc2[0][1], 0, 0, 0);
        acc2[1][0] = __builtin_amdgcn_mfma_f32_16x16x32_bf16(pA1, wA0, acc2[1][0], 0, 0, 0);
        acc2[1][1] = __builtin_amdgcn_mfma_f32_16x16x32_bf16(pA1, wA1, acc2[1][1], 0, 0, 0);
        acc2[0][0] = __builtin_amdgcn_mfma_f32_16x16x32_bf16(pB0, wB0, acc2[0][0], 0, 0, 0);
        acc2[0][1] = __builtin_amdgcn_mfma_f32_16x16x32_bf16(pB0, wB1, acc2[0][1], 0, 0, 0);
        acc2[1][0] = __builtin_amdgcn_mfma_f32_16x16x32_bf16(pB1, wB0, acc2[1][0], 0, 0, 0);
        acc2[1][1] = __builtin_amdgcn_mfma_f32_16x16x32_bf16(pB1, wB1, acc2[1][1], 0, 0, 0);
        PRIO0();
        wA0 = wN0; wA1 = wN1; pA0 = pN0; pA1 = pN1;
        wB0 = wM0; wB1 = wM1; pB0 = pM0; pB1 = pM1;
    }

    // write z
    const int pq = (lane >> 4) << 2;
    #pragma unroll
    for (int p = 0; p < 2; ++p) {
        #pragma unroll
        for (int zi = 0; zi < 2; ++zi) {
            int zc = (zgb + zi) * 16 + lrow;
            float bias = b3[zc];
            #pragma unroll
            for (int rr = 0; rr < 4; ++rr) {
                int pl = (pfb + p) * 16 + pq + rr;
                int ii = (i0 >> 5) + (pl >> 3);
                int jj = (j0 >> 5) + (pl & 7);
                Z[((size_t)ii * L_DIM + jj) * ZD + zc] = acc2[p][zi][rr] + bias;
            }
        }
    }
}

// ---------------------------------------------------------------------------
extern "C" void kernel_launch(void* const* d_in, const int* in_sizes, int n_in,
                              void* d_out, int out_size, void* d_ws, size_t ws_size,
                              hipStream_t stream)
{
    const float* mm    = (const float*)d_in[0];
    const float* gamma = (const float*)d_in[1];
    const float* beta  = (const float*)d_in[2];
    const float* w1    = (const float*)d_in[3];
    const float* b1    = (const float*)d_in[4];
    const float* w2    = (const float*)d_in[5];
    const float* b2    = (const float*)d_in[6];
    const float* w3    = (const float*)d_in[7];
    const float* b3    = (const float*)d_in[8];

    unsigned short* At     = (unsigned short*)d_ws;                  // 12288x512
    unsigned short* Bt     = At + (size_t)MROWS * NB;                // 12288x512
    unsigned short* w3frag = Bt + (size_t)MROWS * NB;                // 131072
    unsigned short* wfrag  = w3frag + 131072;                        // 16384

    prep_kernel<<<576, 256, 0, stream>>>(w1, w2, w3, w3frag, wfrag);
    ln_proj_kernel<<<dim3(16, 192), 256, 0, stream>>>(mm, gamma, beta, wfrag, b1, b2, At, Bt);
    opm_kernel<<<dim3(48, 48), 512, 0, stream>>>(At, Bt, w3frag, b3, (float*)d_out);
}